// Round 1
// baseline (916.961 us; speedup 1.0000x reference)
//
#include <hip/hip_runtime.h>

#define ALPHA 0.9f
#define BETA  0.8f

// ---------------------------------------------------------------------------
// Shapes:
//  state: 128x3x224x224   conv1 w:32x3x8x8 s4 -> f1 128x32x55x55
//  f1 -> conv2 w:64x32x4x4 s2 -> f2 128x64x26x26
//  f2 -> conv3 w:64x64x3x3 s1 -> 128x64x24x24 -> x rows (36864 + 90 history)
//  h1 = x @ w1.T + b1  (128x128), then T=10 LIF recurrence -> out 128x9
// ---------------------------------------------------------------------------

// Transpose conv weights to [k][oc] (wave-uniform k -> scalar weight loads)
// and w2 (256x128) to [k][j] for coalesced reads in the recurrence.
__global__ __launch_bounds__(256) void transpose_weights_kernel(
    const float* __restrict__ cw1, const float* __restrict__ cw2,
    const float* __restrict__ cw3, const float* __restrict__ w2,
    float* __restrict__ wt1, float* __restrict__ wt2,
    float* __restrict__ wt3, float* __restrict__ w2t) {
  int i = blockIdx.x * 256 + threadIdx.x;   // grid covers 36864
  if (i < 6144)  { int k = i >> 5, oc = i & 31;  wt1[k * 32 + oc] = cw1[oc * 192 + k]; }
  if (i < 32768) { int k = i >> 6, oc = i & 63;  wt2[k * 64 + oc] = cw2[oc * 512 + k]; }
  if (i < 36864) { int k = i / 64, oc = i % 64;  wt3[k * 64 + oc] = cw3[oc * 576 + k]; }
  if (i < 32768) { int j = i >> 7, k = i & 127;  w2t[k * 256 + j] = w2[i]; }
}

// conv1: block = (oh, n), 64 threads = ow lanes, 32 acc regs per thread
__global__ __launch_bounds__(64) void conv1_kernel(
    const float* __restrict__ in, const float* __restrict__ wt, // [192][32]
    const float* __restrict__ bias, float* __restrict__ out) {
  int oh = blockIdx.x;          // 0..54
  int n  = blockIdx.y;          // 0..127
  int ow = threadIdx.x;         // active < 55
  float acc[32];
#pragma unroll
  for (int o = 0; o < 32; ++o) acc[o] = 0.f;
  if (ow < 55) {
    const float* ib = in + (size_t)n * 3 * 224 * 224 + (oh * 4) * 224 + ow * 4;
#pragma unroll 1
    for (int c = 0; c < 3; ++c) {
#pragma unroll
      for (int kh = 0; kh < 8; ++kh) {
        const float* row = ib + c * 224 * 224 + kh * 224;
#pragma unroll
        for (int kw = 0; kw < 8; ++kw) {
          float px = row[kw];
          int k = (c * 8 + kh) * 8 + kw;
#pragma unroll
          for (int o = 0; o < 32; ++o)
            acc[o] = fmaf(px, wt[k * 32 + o], acc[o]);
        }
      }
    }
    float* ob = out + ((size_t)(n * 32) * 55 + oh) * 55 + ow;
#pragma unroll
    for (int o = 0; o < 32; ++o) {
      float v = acc[o] + bias[o];
      ob[(size_t)o * 55 * 55] = v > 0.f ? v : 0.f;
    }
  }
}

// conv2: block = (pos-tile, n), 256 threads, each thread one (oh,ow), 64 acc
__global__ __launch_bounds__(256) void conv2_kernel(
    const float* __restrict__ in,  // f1 128x32x55x55
    const float* __restrict__ wt,  // [512][64]
    const float* __restrict__ bias, float* __restrict__ out) {
  int n = blockIdx.y;
  int pos = blockIdx.x * 256 + threadIdx.x;  // active < 676
  float acc[64];
#pragma unroll
  for (int o = 0; o < 64; ++o) acc[o] = 0.f;
  if (pos < 676) {
    int oh = pos / 26, ow = pos % 26;
    const float* ib = in + (size_t)n * 32 * 55 * 55 + (oh * 2) * 55 + ow * 2;
#pragma unroll 1
    for (int c = 0; c < 32; ++c) {
#pragma unroll
      for (int kh = 0; kh < 4; ++kh) {
        const float* row = ib + c * 55 * 55 + kh * 55;
#pragma unroll
        for (int kw = 0; kw < 4; ++kw) {
          float px = row[kw];
          int k = (c * 4 + kh) * 4 + kw;
#pragma unroll
          for (int o = 0; o < 64; ++o)
            acc[o] = fmaf(px, wt[k * 64 + o], acc[o]);
        }
      }
    }
    float* ob = out + ((size_t)(n * 64) * 26 + oh) * 26 + ow;
#pragma unroll
    for (int o = 0; o < 64; ++o) {
      float v = acc[o] + bias[o];
      ob[(size_t)o * 26 * 26] = v > 0.f ? v : 0.f;
    }
  }
}

// conv3: block = (pos-tile, n), 192 threads (3*192 = 576 positions exactly)
// writes straight into x rows (stride 36954), channel-major layout
__global__ __launch_bounds__(192) void conv3_kernel(
    const float* __restrict__ in,  // f2 128x64x26x26
    const float* __restrict__ wt,  // [576][64]
    const float* __restrict__ bias, float* __restrict__ x) {
  int n = blockIdx.y;
  int pos = blockIdx.x * 192 + threadIdx.x;  // < 576 always
  int oh = pos / 24, ow = pos % 24;
  float acc[64];
#pragma unroll
  for (int o = 0; o < 64; ++o) acc[o] = 0.f;
#pragma unroll 1
  for (int c = 0; c < 64; ++c) {
#pragma unroll
    for (int kh = 0; kh < 3; ++kh) {
      const float* row = in + ((size_t)(n * 64 + c) * 26 + oh + kh) * 26 + ow;
#pragma unroll
      for (int kw = 0; kw < 3; ++kw) {
        float px = row[kw];
        int k = (c * 3 + kh) * 3 + kw;
#pragma unroll
        for (int o = 0; o < 64; ++o)
          acc[o] = fmaf(px, wt[k * 64 + o], acc[o]);
      }
    }
  }
  float* xb = x + (size_t)n * 36954 + pos;
#pragma unroll
  for (int o = 0; o < 64; ++o) {
    float v = acc[o] + bias[o];
    xb[(size_t)o * 576] = v > 0.f ? v : 0.f;
  }
}

__global__ __launch_bounds__(256) void histpack_kernel(
    const float* __restrict__ h, float* __restrict__ x) {
  int i = blockIdx.x * 256 + threadIdx.x;
  if (i < 128 * 90) {
    int n = i / 90, k = i % 90;
    x[(size_t)n * 36954 + 36864 + k] = h[i];
  }
}

// FC1 split-K partials: block (kt, b), 128 threads = output j.
// x index is wave-uniform -> scalar loads; w1 per-lane streamed float2.
__global__ __launch_bounds__(128) void fc1_kernel(
    const float* __restrict__ x, const float* __restrict__ w1,
    float* __restrict__ P) {  // P[kt][b][j], kt<16
  int kt = blockIdx.x;
  int b  = blockIdx.y;
  int j  = threadIdx.x;
  int k0 = kt * 2310;
  int k1 = k0 + 2310;
  if (k1 > 36954) k1 = 36954;
  int n2 = (k1 - k0) >> 1;
  const float2* xp = (const float2*)(x  + (size_t)b * 36954 + k0);
  const float2* wp = (const float2*)(w1 + (size_t)j * 36954 + k0);
  float a0 = 0.f, a1 = 0.f;
#pragma unroll 4
  for (int i = 0; i < n2; ++i) {
    float2 xv = xp[i], wv = wp[i];
    a0 = fmaf(xv.x, wv.x, a0);
    a1 = fmaf(xv.y, wv.y, a1);
  }
  P[kt * 16384 + b * 128 + j] = a0 + a1;
}

// Recurrence: one block per batch row; 256 threads own neuron state in regs.
__global__ __launch_bounds__(256) void recur_kernel(
    const float* __restrict__ P,    // [16][128][128]
    const float* __restrict__ b1,
    const float* __restrict__ w2t,  // [128][256]
    const float* __restrict__ b2,
    const float* __restrict__ w3,   // [9][256]
    const float* __restrict__ b3,
    float* __restrict__ out) {      // [128][9]
  int b = blockIdx.x;
  int t = threadIdx.x;
  __shared__ float spk1s[128];
  __shared__ float spk2s[256];
  float h1 = 0.f, mem1 = 0.f, syn1 = 0.f;
  if (t < 128) {
    h1 = b1[t];
#pragma unroll
    for (int kt = 0; kt < 16; ++kt) h1 += P[kt * 16384 + b * 128 + t];
  }
  float mem2 = 0.f, syn2 = 0.f;
  float b2v = b2[t];
  float mem3 = 0.f, syn3 = 0.f, pot = 0.f;
  float b3v = (t < 9) ? b3[t] : 0.f;

  for (int step = 0; step < 10; ++step) {
    if (t < 128) {
      syn1 = ALPHA * syn1 + h1;
      mem1 = BETA * mem1 + syn1;
      float s = (mem1 > 1.0f) ? 1.0f : 0.0f;
      mem1 -= s;
      spk1s[t] = s;
    }
    __syncthreads();
    float h2 = b2v;
#pragma unroll 8
    for (int k = 0; k < 128; ++k)
      h2 = fmaf(spk1s[k], w2t[k * 256 + t], h2);
    syn2 = ALPHA * syn2 + h2;
    mem2 = BETA * mem2 + syn2;
    float s2 = (mem2 > 1.0f) ? 1.0f : 0.0f;
    mem2 -= s2;
    spk2s[t] = s2;
    __syncthreads();
    if (t < 9) {
      float a0 = 0.f, a1 = 0.f, a2 = 0.f, a3 = 0.f;
      const float* wr = w3 + t * 256;
      for (int k = 0; k < 256; k += 4) {
        a0 = fmaf(spk2s[k],     wr[k],     a0);
        a1 = fmaf(spk2s[k + 1], wr[k + 1], a1);
        a2 = fmaf(spk2s[k + 2], wr[k + 2], a2);
        a3 = fmaf(spk2s[k + 3], wr[k + 3], a3);
      }
      float h3 = b3v + (a0 + a1) + (a2 + a3);
      syn3 = ALPHA * syn3 + h3;
      mem3 = BETA * mem3 + syn3;
      pot += mem3;
    }
    __syncthreads();
  }
  if (t < 9) out[b * 9 + t] = pot * 0.1f;
}

extern "C" void kernel_launch(void* const* d_in, const int* in_sizes, int n_in,
                              void* d_out, int out_size, void* d_ws, size_t ws_size,
                              hipStream_t stream) {
  const float* state   = (const float*)d_in[0];
  const float* history = (const float*)d_in[1];
  const float* cw1 = (const float*)d_in[2];
  const float* cb1 = (const float*)d_in[3];
  const float* cw2 = (const float*)d_in[4];
  const float* cb2 = (const float*)d_in[5];
  const float* cw3 = (const float*)d_in[6];
  const float* cb3 = (const float*)d_in[7];
  const float* w1  = (const float*)d_in[8];
  const float* b1  = (const float*)d_in[9];
  const float* w2  = (const float*)d_in[10];
  const float* b2  = (const float*)d_in[11];
  const float* w3  = (const float*)d_in[12];
  const float* b3  = (const float*)d_in[13];
  float* out = (float*)d_out;
  char* ws = (char*)d_ws;

  // workspace layout (bytes); x reuses the f1 region (f1 dead after conv2)
  float* f1  = (float*)(ws + 0);          // 128*32*55*55*4 = 49,561,600
  float* f2  = (float*)(ws + 49561600);   // 128*64*26*26*4 = 22,151,168
  float* xb  = (float*)(ws + 0);          // 128*36954*4    = 18,920,448
  float* P   = (float*)(ws + 71712768);   // 16*128*128*4   =  1,048,576
  float* wt1 = (float*)(ws + 72761344);   // 24,576
  float* wt2 = (float*)(ws + 72785920);   // 131,072
  float* wt3 = (float*)(ws + 72916992);   // 147,456
  float* w2t = (float*)(ws + 73064448);   // 131,072

  transpose_weights_kernel<<<144, 256, 0, stream>>>(cw1, cw2, cw3, w2,
                                                    wt1, wt2, wt3, w2t);
  conv1_kernel<<<dim3(55, 128), 64, 0, stream>>>(state, wt1, cb1, f1);
  conv2_kernel<<<dim3(3, 128), 256, 0, stream>>>(f1, wt2, cb2, f2);
  conv3_kernel<<<dim3(3, 128), 192, 0, stream>>>(f2, wt3, cb3, xb);
  histpack_kernel<<<45, 256, 0, stream>>>(history, xb);
  fc1_kernel<<<dim3(16, 128), 128, 0, stream>>>(xb, w1, P);
  recur_kernel<<<128, 256, 0, stream>>>(P, b1, w2t, b2, w3, b3, out);
}

// Round 2
// 602.826 us; speedup vs baseline: 1.5211x; 1.5211x over previous
//
#include <hip/hip_runtime.h>

#define ALPHA 0.9f
#define BETA  0.8f

// ---------------------------------------------------------------------------
// state: 128x3x224x224  conv1 32x3x8x8 s4 -> f1 128x32x55x55
// f1 -> conv2 64x32x4x4 s2 -> f2 128x64x26x26
// f2 -> conv3 64x64x3x3 s1 -> x rows (36864 + 90 history) = 36954
// h1 = x @ w1.T + b1 (128x128), T=10 LIF recurrence -> out 128x9
// ---------------------------------------------------------------------------

// Small-weight transposes: conv weights -> [k][oc] (wave-uniform k -> scalar
// loads), w2 (256x128) -> [k][j].
__global__ __launch_bounds__(256) void transpose_weights_kernel(
    const float* __restrict__ cw1, const float* __restrict__ cw2,
    const float* __restrict__ cw3, const float* __restrict__ w2,
    float* __restrict__ wt1, float* __restrict__ wt2,
    float* __restrict__ wt3, float* __restrict__ w2t) {
  int i = blockIdx.x * 256 + threadIdx.x;   // grid covers 36864
  if (i < 6144)  { int k = i >> 5, oc = i & 31;  wt1[k * 32 + oc] = cw1[oc * 192 + k]; }
  if (i < 32768) { int k = i >> 6, oc = i & 63;  wt2[k * 64 + oc] = cw2[oc * 512 + k]; }
  if (i < 36864) { int k = i / 64, oc = i % 64;  wt3[k * 64 + oc] = cw3[oc * 576 + k]; }
  if (i < 32768) { int j = i >> 7, k = i & 127;  w2t[k * 256 + j] = w2[i]; }
}

// w1 (128 x 36954) -> w1t (36954 x 128), LDS-tiled for coalescing both sides.
__global__ __launch_bounds__(256) void transpose_w1_kernel(
    const float* __restrict__ w1, float* __restrict__ w1t) {
  __shared__ float tile[32][33];
  int k0 = blockIdx.x * 32;                 // 1155 blocks
  int j0 = blockIdx.y * 32;                 // 4 blocks
  int tx = threadIdx.x & 31, ty = threadIdx.x >> 5;  // ty 0..7
#pragma unroll
  for (int i = 0; i < 4; ++i) {
    int j = j0 + ty + i * 8, k = k0 + tx;
    tile[ty + i * 8][tx] = (k < 36954) ? w1[(size_t)j * 36954 + k] : 0.f;
  }
  __syncthreads();
#pragma unroll
  for (int i = 0; i < 4; ++i) {
    int k = k0 + ty + i * 8, j = j0 + tx;
    if (k < 36954) w1t[(size_t)k * 128 + j] = tile[tx][ty + i * 8];
  }
}

// conv1: block = (oh, n), 64 threads = ow lanes, 32 acc regs per thread
__global__ __launch_bounds__(64) void conv1_kernel(
    const float* __restrict__ in, const float* __restrict__ wt, // [192][32]
    const float* __restrict__ bias, float* __restrict__ out) {
  int oh = blockIdx.x;          // 0..54
  int n  = blockIdx.y;          // 0..127
  int ow = threadIdx.x;         // active < 55
  float acc[32];
#pragma unroll
  for (int o = 0; o < 32; ++o) acc[o] = 0.f;
  if (ow < 55) {
    const float* ib = in + (size_t)n * 3 * 224 * 224 + (oh * 4) * 224 + ow * 4;
#pragma unroll 1
    for (int c = 0; c < 3; ++c) {
#pragma unroll
      for (int kh = 0; kh < 8; ++kh) {
        const float* row = ib + c * 224 * 224 + kh * 224;
#pragma unroll
        for (int kw = 0; kw < 8; ++kw) {
          float px = row[kw];
          int k = (c * 8 + kh) * 8 + kw;
#pragma unroll
          for (int o = 0; o < 32; ++o)
            acc[o] = fmaf(px, wt[k * 32 + o], acc[o]);
        }
      }
    }
    float* ob = out + ((size_t)(n * 32) * 55 + oh) * 55 + ow;
#pragma unroll
    for (int o = 0; o < 32; ++o) {
      float v = acc[o] + bias[o];
      ob[(size_t)o * 55 * 55] = v > 0.f ? v : 0.f;
    }
  }
}

// conv2: block = (pos-tile, n, oc-half), 256 threads, 32 acc per thread
__global__ __launch_bounds__(256) void conv2_kernel(
    const float* __restrict__ in,  // f1 128x32x55x55
    const float* __restrict__ wt,  // [512][64]
    const float* __restrict__ bias, float* __restrict__ out) {
  int n = blockIdx.y;
  int ob0 = blockIdx.z * 32;                 // 0 or 32
  int pos = blockIdx.x * 256 + threadIdx.x;  // active < 676
  float acc[32];
#pragma unroll
  for (int o = 0; o < 32; ++o) acc[o] = 0.f;
  if (pos < 676) {
    int oh = pos / 26, ow = pos % 26;
    const float* ib = in + (size_t)n * 32 * 55 * 55 + (oh * 2) * 55 + ow * 2;
#pragma unroll 1
    for (int c = 0; c < 32; ++c) {
#pragma unroll
      for (int kh = 0; kh < 4; ++kh) {
        const float* row = ib + c * 55 * 55 + kh * 55;
#pragma unroll
        for (int kw = 0; kw < 4; ++kw) {
          float px = row[kw];
          int k = (c * 4 + kh) * 4 + kw;
#pragma unroll
          for (int o = 0; o < 32; ++o)
            acc[o] = fmaf(px, wt[k * 64 + ob0 + o], acc[o]);
        }
      }
    }
    float* obp = out + ((size_t)(n * 64 + ob0) * 26 + oh) * 26 + ow;
#pragma unroll
    for (int o = 0; o < 32; ++o) {
      float v = acc[o] + bias[ob0 + o];
      obp[(size_t)o * 26 * 26] = v > 0.f ? v : 0.f;
    }
  }
}

// conv3: block = (pos-tile, n, oc-half), 192 threads (3*192=576 positions)
// writes straight into x rows (stride 36954), channel-major layout
__global__ __launch_bounds__(192) void conv3_kernel(
    const float* __restrict__ in,  // f2 128x64x26x26
    const float* __restrict__ wt,  // [576][64]
    const float* __restrict__ bias, float* __restrict__ x) {
  int n = blockIdx.y;
  int ob0 = blockIdx.z * 32;                 // 0 or 32
  int pos = blockIdx.x * 192 + threadIdx.x;  // < 576 always
  int oh = pos / 24, ow = pos % 24;
  float acc[32];
#pragma unroll
  for (int o = 0; o < 32; ++o) acc[o] = 0.f;
#pragma unroll 1
  for (int c = 0; c < 64; ++c) {
#pragma unroll
    for (int kh = 0; kh < 3; ++kh) {
      const float* row = in + ((size_t)(n * 64 + c) * 26 + oh + kh) * 26 + ow;
#pragma unroll
      for (int kw = 0; kw < 3; ++kw) {
        float px = row[kw];
        int k = (c * 3 + kh) * 3 + kw;
#pragma unroll
        for (int o = 0; o < 32; ++o)
          acc[o] = fmaf(px, wt[k * 64 + ob0 + o], acc[o]);
      }
    }
  }
  float* xb = x + (size_t)n * 36954 + pos;
#pragma unroll
  for (int o = 0; o < 32; ++o) {
    float v = acc[o] + bias[ob0 + o];
    xb[(size_t)(ob0 + o) * 576] = v > 0.f ? v : 0.f;
  }
}

__global__ __launch_bounds__(256) void histpack_kernel(
    const float* __restrict__ h, float* __restrict__ x) {
  int i = blockIdx.x * 256 + threadIdx.x;
  if (i < 128 * 90) {
    int n = i / 90, k = i % 90;
    x[(size_t)n * 36954 + 36864 + k] = h[i];
  }
}

// FC1 split-K tiled GEMM: h1[128b x 128j] partials.
// Grid (kt=58, bt=4). 256 thr = 128 j-lanes x 2 b-halves; 16 b-accs each.
// w1t[k][j] loads coalesced across j; x staged in LDS, broadcast reads.
#define FC1_KT 58
__global__ __launch_bounds__(256) void fc1_kernel(
    const float* __restrict__ x, const float* __restrict__ w1t,
    float* __restrict__ P) {  // P[kt][b][j]
  int kt = blockIdx.x;        // 0..57, 5 chunks of 128 k each
  int b0 = blockIdx.y * 32;
  int j  = threadIdx.x & 127;
  int bh = threadIdx.x >> 7;  // 0..1
  __shared__ float xs[32][128];
  float acc[16];
#pragma unroll
  for (int i = 0; i < 16; ++i) acc[i] = 0.f;
  int c0 = kt * 5;
  int c1 = c0 + 5; if (c1 > 289) c1 = 289;   // 289 chunks cover 36954
  for (int ch = c0; ch < c1; ++ch) {
    int k0 = ch * 128;
    int rem = 36954 - k0; if (rem > 128) rem = 128;
    __syncthreads();
#pragma unroll
    for (int i = 0; i < 16; ++i) {
      int idx = threadIdx.x + i * 256;
      int r = idx >> 7, c = idx & 127;
      xs[r][c] = (c < rem) ? x[(size_t)(b0 + r) * 36954 + k0 + c] : 0.f;
    }
    __syncthreads();
    for (int kk = 0; kk < rem; ++kk) {
      float wv = w1t[(size_t)(k0 + kk) * 128 + j];
#pragma unroll
      for (int i = 0; i < 16; ++i)
        acc[i] = fmaf(xs[bh * 16 + i][kk], wv, acc[i]);
    }
  }
#pragma unroll
  for (int i = 0; i < 16; ++i)
    P[((size_t)kt * 128 + b0 + bh * 16 + i) * 128 + j] = acc[i];
}

// Recurrence: one block per batch row; 256 threads own neuron state in regs.
__global__ __launch_bounds__(256) void recur_kernel(
    const float* __restrict__ P,    // [58][128][128]
    const float* __restrict__ b1,
    const float* __restrict__ w2t,  // [128][256]
    const float* __restrict__ b2,
    const float* __restrict__ w3,   // [9][256]
    const float* __restrict__ b3,
    float* __restrict__ out) {      // [128][9]
  int b = blockIdx.x;
  int t = threadIdx.x;
  __shared__ float spk1s[128];
  __shared__ float spk2s[256];
  float h1 = 0.f, mem1 = 0.f, syn1 = 0.f;
  if (t < 128) {
    h1 = b1[t];
    for (int kt = 0; kt < FC1_KT; ++kt)
      h1 += P[((size_t)kt * 128 + b) * 128 + t];
  }
  float mem2 = 0.f, syn2 = 0.f;
  float b2v = b2[t];
  float mem3 = 0.f, syn3 = 0.f, pot = 0.f;
  float b3v = (t < 9) ? b3[t] : 0.f;

  for (int step = 0; step < 10; ++step) {
    if (t < 128) {
      syn1 = ALPHA * syn1 + h1;
      mem1 = BETA * mem1 + syn1;
      float s = (mem1 > 1.0f) ? 1.0f : 0.0f;
      mem1 -= s;
      spk1s[t] = s;
    }
    __syncthreads();
    float h2 = b2v;
#pragma unroll 8
    for (int k = 0; k < 128; ++k)
      h2 = fmaf(spk1s[k], w2t[k * 256 + t], h2);
    syn2 = ALPHA * syn2 + h2;
    mem2 = BETA * mem2 + syn2;
    float s2 = (mem2 > 1.0f) ? 1.0f : 0.0f;
    mem2 -= s2;
    spk2s[t] = s2;
    __syncthreads();
    if (t < 9) {
      float a0 = 0.f, a1 = 0.f, a2 = 0.f, a3 = 0.f;
      const float* wr = w3 + t * 256;
      for (int k = 0; k < 256; k += 4) {
        a0 = fmaf(spk2s[k],     wr[k],     a0);
        a1 = fmaf(spk2s[k + 1], wr[k + 1], a1);
        a2 = fmaf(spk2s[k + 2], wr[k + 2], a2);
        a3 = fmaf(spk2s[k + 3], wr[k + 3], a3);
      }
      float h3 = b3v + (a0 + a1) + (a2 + a3);
      syn3 = ALPHA * syn3 + h3;
      mem3 = BETA * mem3 + syn3;
      pot += mem3;
    }
    __syncthreads();
  }
  if (t < 9) out[b * 9 + t] = pot * 0.1f;
}

extern "C" void kernel_launch(void* const* d_in, const int* in_sizes, int n_in,
                              void* d_out, int out_size, void* d_ws, size_t ws_size,
                              hipStream_t stream) {
  const float* state   = (const float*)d_in[0];
  const float* history = (const float*)d_in[1];
  const float* cw1 = (const float*)d_in[2];
  const float* cb1 = (const float*)d_in[3];
  const float* cw2 = (const float*)d_in[4];
  const float* cb2 = (const float*)d_in[5];
  const float* cw3 = (const float*)d_in[6];
  const float* cb3 = (const float*)d_in[7];
  const float* w1  = (const float*)d_in[8];
  const float* b1  = (const float*)d_in[9];
  const float* w2  = (const float*)d_in[10];
  const float* b2  = (const float*)d_in[11];
  const float* w3  = (const float*)d_in[12];
  const float* b3  = (const float*)d_in[13];
  float* out = (float*)d_out;
  char* ws = (char*)d_ws;

  // workspace layout (bytes):
  //  [0, 49561600)           f1 (dead after conv2); xb = [0,18920448) after conv3
  //  [18920448, 37840896)    w1t (written after conv2, inside dead f1)
  //  [49561600, 71712768)    f2 (dead after conv3); P = [49561600, +3801088)
  //  [71712768, ...)         small transposed weights
  float* f1  = (float*)(ws + 0);
  float* xb  = (float*)(ws + 0);
  float* w1t = (float*)(ws + 18920448);
  float* f2  = (float*)(ws + 49561600);
  float* P   = (float*)(ws + 49561600);   // 58*128*128*4 = 3,801,088
  float* wt1 = (float*)(ws + 71712768);   // 24,576
  float* wt2 = (float*)(ws + 71737344);   // 131,072
  float* wt3 = (float*)(ws + 71868416);   // 147,456
  float* w2t = (float*)(ws + 72015872);   // 131,072  (end 72,146,944)

  transpose_weights_kernel<<<144, 256, 0, stream>>>(cw1, cw2, cw3, w2,
                                                    wt1, wt2, wt3, w2t);
  conv1_kernel<<<dim3(55, 128), 64, 0, stream>>>(state, wt1, cb1, f1);
  conv2_kernel<<<dim3(3, 128, 2), 256, 0, stream>>>(f1, wt2, cb2, f2);
  transpose_w1_kernel<<<dim3(1155, 4), 256, 0, stream>>>(w1, w1t);
  conv3_kernel<<<dim3(3, 128, 2), 192, 0, stream>>>(f2, wt3, cb3, xb);
  histpack_kernel<<<45, 256, 0, stream>>>(history, xb);
  fc1_kernel<<<dim3(FC1_KT, 4), 256, 0, stream>>>(xb, w1t, P);
  recur_kernel<<<128, 256, 0, stream>>>(P, b1, w2t, b2, w3, b3, out);
}

// Round 3
// 532.359 us; speedup vs baseline: 1.7224x; 1.1324x over previous
//
#include <hip/hip_runtime.h>

#define ALPHA 0.9f
#define BETA  0.8f

// ---------------------------------------------------------------------------
// state: 128x3x224x224  conv1 32x3x8x8 s4 -> f1 128x32x55x55
// f1 -> conv2 64x32x4x4 s2 -> f2 128x64x26x26
// f2 -> conv3 64x64x3x3 s1 -> x rows (36864 + 90 history) = 36954
// h1 = x @ w1.T + b1 (128x128), T=10 LIF recurrence -> out 128x9
// ---------------------------------------------------------------------------

__global__ __launch_bounds__(256) void transpose_weights_kernel(
    const float* __restrict__ cw1, const float* __restrict__ cw2,
    const float* __restrict__ cw3, const float* __restrict__ w2,
    float* __restrict__ wt1, float* __restrict__ wt2,
    float* __restrict__ wt3, float* __restrict__ w2t) {
  int i = blockIdx.x * 256 + threadIdx.x;   // grid covers 36864
  if (i < 6144)  { int k = i >> 5, oc = i & 31;  wt1[k * 32 + oc] = cw1[oc * 192 + k]; }
  if (i < 32768) { int k = i >> 6, oc = i & 63;  wt2[k * 64 + oc] = cw2[oc * 512 + k]; }
  if (i < 36864) { int k = i / 64, oc = i % 64;  wt3[k * 64 + oc] = cw3[oc * 576 + k]; }
  if (i < 32768) { int j = i >> 7, k = i & 127;  w2t[k * 256 + j] = w2[i]; }
}

// w1 (128 x 36954) -> w1t (36954 x 128), LDS-tiled.
__global__ __launch_bounds__(256) void transpose_w1_kernel(
    const float* __restrict__ w1, float* __restrict__ w1t) {
  __shared__ float tile[32][33];
  int k0 = blockIdx.x * 32;                 // 1155 blocks
  int j0 = blockIdx.y * 32;                 // 4 blocks
  int tx = threadIdx.x & 31, ty = threadIdx.x >> 5;  // ty 0..7
#pragma unroll
  for (int i = 0; i < 4; ++i) {
    int j = j0 + ty + i * 8, k = k0 + tx;
    tile[ty + i * 8][tx] = (k < 36954) ? w1[(size_t)j * 36954 + k] : 0.f;
  }
  __syncthreads();
#pragma unroll
  for (int i = 0; i < 4; ++i) {
    int k = k0 + ty + i * 8, j = j0 + tx;
    if (k < 36954) w1t[(size_t)k * 128 + j] = tile[tx][ty + i * 8];
  }
}

// conv1: block = (oh, n), 64 threads = ow lanes, 32 acc regs per thread
__global__ __launch_bounds__(64) void conv1_kernel(
    const float* __restrict__ in, const float* __restrict__ wt, // [192][32]
    const float* __restrict__ bias, float* __restrict__ out) {
  int oh = blockIdx.x;          // 0..54
  int n  = blockIdx.y;          // 0..127
  int ow = threadIdx.x;         // active < 55
  float acc[32];
#pragma unroll
  for (int o = 0; o < 32; ++o) acc[o] = 0.f;
  if (ow < 55) {
    const float* ib = in + (size_t)n * 3 * 224 * 224 + (oh * 4) * 224 + ow * 4;
#pragma unroll 1
    for (int c = 0; c < 3; ++c) {
#pragma unroll
      for (int kh = 0; kh < 8; ++kh) {
        const float* row = ib + c * 224 * 224 + kh * 224;
#pragma unroll
        for (int kw = 0; kw < 8; ++kw) {
          float px = row[kw];
          int k = (c * 8 + kh) * 8 + kw;
#pragma unroll
          for (int o = 0; o < 32; ++o)
            acc[o] = fmaf(px, wt[k * 32 + o], acc[o]);
        }
      }
    }
    float* ob = out + ((size_t)(n * 32) * 55 + oh) * 55 + ow;
#pragma unroll
    for (int o = 0; o < 32; ++o) {
      float v = acc[o] + bias[o];
      ob[(size_t)o * 55 * 55] = v > 0.f ? v : 0.f;
    }
  }
}

// conv2: 64-thr blocks, grid (pos-tile=11, n=128, ocq=4), 16 accs/thread
__global__ __launch_bounds__(64) void conv2_kernel(
    const float* __restrict__ in,  // f1 128x32x55x55
    const float* __restrict__ wt,  // [512][64]
    const float* __restrict__ bias, float* __restrict__ out) {
  int n = blockIdx.y;
  int ob0 = blockIdx.z * 16;                 // 0,16,32,48
  int pos = blockIdx.x * 64 + threadIdx.x;   // active < 676
  float acc[16];
#pragma unroll
  for (int o = 0; o < 16; ++o) acc[o] = 0.f;
  if (pos < 676) {
    int oh = pos / 26, ow = pos % 26;
    const float* ib = in + (size_t)n * 32 * 55 * 55 + (oh * 2) * 55 + ow * 2;
    const float* wb = wt + ob0;
#pragma unroll 2
    for (int c = 0; c < 32; ++c) {
#pragma unroll
      for (int kh = 0; kh < 4; ++kh) {
        const float* row = ib + c * 55 * 55 + kh * 55;
#pragma unroll
        for (int kw = 0; kw < 4; ++kw) {
          float px = row[kw];
          int k = (c * 4 + kh) * 4 + kw;
#pragma unroll
          for (int o = 0; o < 16; ++o)
            acc[o] = fmaf(px, wb[k * 64 + o], acc[o]);
        }
      }
    }
    float* obp = out + ((size_t)(n * 64 + ob0) * 26 + oh) * 26 + ow;
#pragma unroll
    for (int o = 0; o < 16; ++o) {
      float v = acc[o] + bias[ob0 + o];
      obp[(size_t)o * 26 * 26] = v > 0.f ? v : 0.f;
    }
  }
}

// conv3: 64-thr blocks, grid (pos-tile=9, n=128, ocq=4), 16 accs/thread
__global__ __launch_bounds__(64) void conv3_kernel(
    const float* __restrict__ in,  // f2 128x64x26x26
    const float* __restrict__ wt,  // [576][64]
    const float* __restrict__ bias, float* __restrict__ x) {
  int n = blockIdx.y;
  int ob0 = blockIdx.z * 16;                 // 0,16,32,48
  int pos = blockIdx.x * 64 + threadIdx.x;   // < 576 always
  int oh = pos / 24, ow = pos % 24;
  float acc[16];
#pragma unroll
  for (int o = 0; o < 16; ++o) acc[o] = 0.f;
  const float* wb = wt + ob0;
#pragma unroll 2
  for (int c = 0; c < 64; ++c) {
#pragma unroll
    for (int kh = 0; kh < 3; ++kh) {
      const float* row = in + ((size_t)(n * 64 + c) * 26 + oh + kh) * 26 + ow;
#pragma unroll
      for (int kw = 0; kw < 3; ++kw) {
        float px = row[kw];
        int k = (c * 3 + kh) * 3 + kw;
#pragma unroll
        for (int o = 0; o < 16; ++o)
          acc[o] = fmaf(px, wb[k * 64 + o], acc[o]);
      }
    }
  }
  float* xb = x + (size_t)n * 36954 + pos;
#pragma unroll
  for (int o = 0; o < 16; ++o) {
    float v = acc[o] + bias[ob0 + o];
    xb[(size_t)(ob0 + o) * 576] = v > 0.f ? v : 0.f;
  }
}

__global__ __launch_bounds__(256) void histpack_kernel(
    const float* __restrict__ h, float* __restrict__ x) {
  int i = blockIdx.x * 256 + threadIdx.x;
  if (i < 128 * 90) {
    int n = i / 90, k = i % 90;
    x[(size_t)n * 36954 + 36864 + k] = h[i];
  }
}

// FC1 split-K tiled GEMM: h1[128b x 128j] partials.
// Grid (kt=58, bt=4). 256 thr = 128 j-lanes x 2 b-halves; 16 b-accs each.
// xs reads vectorized float4 over kk (4x fewer LDS instructions).
#define FC1_KT 58
__global__ __launch_bounds__(256) void fc1_kernel(
    const float* __restrict__ x, const float* __restrict__ w1t,
    float* __restrict__ P) {  // P[kt][b][j]
  int kt = blockIdx.x;        // 0..57, 5 chunks of 128 k each
  int b0 = blockIdx.y * 32;
  int j  = threadIdx.x & 127;
  int bh = threadIdx.x >> 7;  // 0..1
  __shared__ float xs[32][128];
  float acc[16];
#pragma unroll
  for (int i = 0; i < 16; ++i) acc[i] = 0.f;
  int c0 = kt * 5;
  int c1 = c0 + 5; if (c1 > 289) c1 = 289;   // 289 chunks cover 36954
  for (int ch = c0; ch < c1; ++ch) {
    int k0 = ch * 128;
    int rem = 36954 - k0; if (rem > 128) rem = 128;
    __syncthreads();
#pragma unroll
    for (int i = 0; i < 16; ++i) {
      int idx = threadIdx.x + i * 256;
      int r = idx >> 7, c = idx & 127;
      xs[r][c] = (c < rem) ? x[(size_t)(b0 + r) * 36954 + k0 + c] : 0.f;
    }
    __syncthreads();
    int rem4 = rem & ~3;
    for (int kk = 0; kk < rem4; kk += 4) {
      float wv0 = w1t[(size_t)(k0 + kk + 0) * 128 + j];
      float wv1 = w1t[(size_t)(k0 + kk + 1) * 128 + j];
      float wv2 = w1t[(size_t)(k0 + kk + 2) * 128 + j];
      float wv3 = w1t[(size_t)(k0 + kk + 3) * 128 + j];
#pragma unroll
      for (int i = 0; i < 16; ++i) {
        float4 xv = *(const float4*)&xs[bh * 16 + i][kk];
        acc[i] = fmaf(xv.x, wv0, acc[i]);
        acc[i] = fmaf(xv.y, wv1, acc[i]);
        acc[i] = fmaf(xv.z, wv2, acc[i]);
        acc[i] = fmaf(xv.w, wv3, acc[i]);
      }
    }
    for (int kk = rem4; kk < rem; ++kk) {
      float wv = w1t[(size_t)(k0 + kk) * 128 + j];
#pragma unroll
      for (int i = 0; i < 16; ++i)
        acc[i] = fmaf(xs[bh * 16 + i][kk], wv, acc[i]);
    }
  }
#pragma unroll
  for (int i = 0; i < 16; ++i)
    P[((size_t)kt * 128 + b0 + bh * 16 + i) * 128 + j] = acc[i];
}

// Recurrence: one block per batch row; 256 threads own neuron state in regs.
__global__ __launch_bounds__(256) void recur_kernel(
    const float* __restrict__ P,    // [58][128][128]
    const float* __restrict__ b1,
    const float* __restrict__ w2t,  // [128][256]
    const float* __restrict__ b2,
    const float* __restrict__ w3,   // [9][256]
    const float* __restrict__ b3,
    float* __restrict__ out) {      // [128][9]
  int b = blockIdx.x;
  int t = threadIdx.x;
  __shared__ float spk1s[128];
  __shared__ float spk2s[256];
  float h1 = 0.f, mem1 = 0.f, syn1 = 0.f;
  if (t < 128) {
    h1 = b1[t];
    for (int kt = 0; kt < FC1_KT; ++kt)
      h1 += P[((size_t)kt * 128 + b) * 128 + t];
  }
  float mem2 = 0.f, syn2 = 0.f;
  float b2v = b2[t];
  float mem3 = 0.f, syn3 = 0.f, pot = 0.f;
  float b3v = (t < 9) ? b3[t] : 0.f;

  for (int step = 0; step < 10; ++step) {
    if (t < 128) {
      syn1 = ALPHA * syn1 + h1;
      mem1 = BETA * mem1 + syn1;
      float s = (mem1 > 1.0f) ? 1.0f : 0.0f;
      mem1 -= s;
      spk1s[t] = s;
    }
    __syncthreads();
    float h2 = b2v;
#pragma unroll 8
    for (int k = 0; k < 128; ++k)
      h2 = fmaf(spk1s[k], w2t[k * 256 + t], h2);
    syn2 = ALPHA * syn2 + h2;
    mem2 = BETA * mem2 + syn2;
    float s2 = (mem2 > 1.0f) ? 1.0f : 0.0f;
    mem2 -= s2;
    spk2s[t] = s2;
    __syncthreads();
    if (t < 9) {
      float a0 = 0.f, a1 = 0.f, a2 = 0.f, a3 = 0.f;
      const float* wr = w3 + t * 256;
      for (int k = 0; k < 256; k += 4) {
        a0 = fmaf(spk2s[k],     wr[k],     a0);
        a1 = fmaf(spk2s[k + 1], wr[k + 1], a1);
        a2 = fmaf(spk2s[k + 2], wr[k + 2], a2);
        a3 = fmaf(spk2s[k + 3], wr[k + 3], a3);
      }
      float h3 = b3v + (a0 + a1) + (a2 + a3);
      syn3 = ALPHA * syn3 + h3;
      mem3 = BETA * mem3 + syn3;
      pot += mem3;
    }
    __syncthreads();
  }
  if (t < 9) out[b * 9 + t] = pot * 0.1f;
}

extern "C" void kernel_launch(void* const* d_in, const int* in_sizes, int n_in,
                              void* d_out, int out_size, void* d_ws, size_t ws_size,
                              hipStream_t stream) {
  const float* state   = (const float*)d_in[0];
  const float* history = (const float*)d_in[1];
  const float* cw1 = (const float*)d_in[2];
  const float* cb1 = (const float*)d_in[3];
  const float* cw2 = (const float*)d_in[4];
  const float* cb2 = (const float*)d_in[5];
  const float* cw3 = (const float*)d_in[6];
  const float* cb3 = (const float*)d_in[7];
  const float* w1  = (const float*)d_in[8];
  const float* b1  = (const float*)d_in[9];
  const float* w2  = (const float*)d_in[10];
  const float* b2  = (const float*)d_in[11];
  const float* w3  = (const float*)d_in[12];
  const float* b3  = (const float*)d_in[13];
  float* out = (float*)d_out;
  char* ws = (char*)d_ws;

  // workspace layout (bytes):
  //  [0, 49561600)           f1 (dead after conv2); xb = [0,18920448) after conv3
  //  [18920448, 37840896)    w1t (written after conv2, inside dead f1)
  //  [49561600, 71712768)    f2 (dead after conv3); P = [49561600, +3801088)
  //  [71712768, ...)         small transposed weights
  float* f1  = (float*)(ws + 0);
  float* xb  = (float*)(ws + 0);
  float* w1t = (float*)(ws + 18920448);
  float* f2  = (float*)(ws + 49561600);
  float* P   = (float*)(ws + 49561600);   // 58*128*128*4 = 3,801,088
  float* wt1 = (float*)(ws + 71712768);   // 24,576
  float* wt2 = (float*)(ws + 71737344);   // 131,072
  float* wt3 = (float*)(ws + 71868416);   // 147,456
  float* w2t = (float*)(ws + 72015872);   // 131,072  (end 72,146,944)

  transpose_weights_kernel<<<144, 256, 0, stream>>>(cw1, cw2, cw3, w2,
                                                    wt1, wt2, wt3, w2t);
  conv1_kernel<<<dim3(55, 128), 64, 0, stream>>>(state, wt1, cb1, f1);
  conv2_kernel<<<dim3(11, 128, 4), 64, 0, stream>>>(f1, wt2, cb2, f2);
  transpose_w1_kernel<<<dim3(1155, 4), 256, 0, stream>>>(w1, w1t);
  conv3_kernel<<<dim3(9, 128, 4), 64, 0, stream>>>(f2, wt3, cb3, xb);
  histpack_kernel<<<45, 256, 0, stream>>>(history, xb);
  fc1_kernel<<<dim3(FC1_KT, 4), 256, 0, stream>>>(xb, w1t, P);
  recur_kernel<<<128, 256, 0, stream>>>(P, b1, w2t, b2, w3, b3, out);
}

// Round 4
// 467.036 us; speedup vs baseline: 1.9634x; 1.1399x over previous
//
#include <hip/hip_runtime.h>

#define ALPHA 0.9f
#define BETA  0.8f
#define XS 36960   // padded row stride for x and w1p (multiple of 4, >= 36954)

// ---------------------------------------------------------------------------
// state: 128x3x224x224  conv1 32x3x8x8 s4 -> f1 128x32x55x55
// f1 -> conv2 64x32x4x4 s2 -> f2 128x64x26x26
// f2 -> conv3 64x64x3x3 s1 -> x rows (36864 + 90 history, pad to 36960)
// h1 = x @ w1.T + b1 (128x128), T=10 LIF recurrence -> out 128x9
// ---------------------------------------------------------------------------

__global__ __launch_bounds__(256) void transpose_weights_kernel(
    const float* __restrict__ cw1, const float* __restrict__ cw2,
    const float* __restrict__ cw3, const float* __restrict__ w2,
    float* __restrict__ wt1, float* __restrict__ wt2,
    float* __restrict__ wt3, float* __restrict__ w2t) {
  int i = blockIdx.x * 256 + threadIdx.x;   // grid covers 36864
  if (i < 6144)  { int k = i >> 5, oc = i & 31;  wt1[k * 32 + oc] = cw1[oc * 192 + k]; }
  if (i < 32768) { int k = i >> 6, oc = i & 63;  wt2[k * 64 + oc] = cw2[oc * 512 + k]; }
  if (i < 36864) { int k = i / 64, oc = i % 64;  wt3[k * 64 + oc] = cw3[oc * 576 + k]; }
  if (i < 32768) { int j = i >> 7, k = i & 127;  w2t[k * 256 + j] = w2[i]; }
}

// Copy w1 (128 x 36954) into padded rows (128 x 36960), zero tail.
__global__ __launch_bounds__(256) void pad_w1_kernel(
    const float* __restrict__ w1, float* __restrict__ w1p) {
  int i = blockIdx.x * 256 + threadIdx.x;   // float2 slots: 128 * 18480
  if (i < 128 * 18480) {
    int j = i / 18480, c = i - j * 18480;
    float2 v;
    if (c < 18477) v = *(const float2*)&w1[(size_t)j * 36954 + c * 2];
    else v = make_float2(0.f, 0.f);
    *(float2*)&w1p[(size_t)j * XS + c * 2] = v;
  }
}

// conv1: block = (oh, n), 64 threads = ow lanes, 32 acc regs per thread
__global__ __launch_bounds__(64) void conv1_kernel(
    const float* __restrict__ in, const float* __restrict__ wt, // [192][32]
    const float* __restrict__ bias, float* __restrict__ out) {
  int oh = blockIdx.x;          // 0..54
  int n  = blockIdx.y;          // 0..127
  int ow = threadIdx.x;         // active < 55
  float acc[32];
#pragma unroll
  for (int o = 0; o < 32; ++o) acc[o] = 0.f;
  if (ow < 55) {
    const float* ib = in + (size_t)n * 3 * 224 * 224 + (oh * 4) * 224 + ow * 4;
#pragma unroll 1
    for (int c = 0; c < 3; ++c) {
#pragma unroll
      for (int kh = 0; kh < 8; ++kh) {
        const float* row = ib + c * 224 * 224 + kh * 224;
#pragma unroll
        for (int kw = 0; kw < 8; ++kw) {
          float px = row[kw];
          int k = (c * 8 + kh) * 8 + kw;
#pragma unroll
          for (int o = 0; o < 32; ++o)
            acc[o] = fmaf(px, wt[k * 32 + o], acc[o]);
        }
      }
    }
    float* ob = out + ((size_t)(n * 32) * 55 + oh) * 55 + ow;
#pragma unroll
    for (int o = 0; o < 32; ++o) {
      float v = acc[o] + bias[o];
      ob[(size_t)o * 55 * 55] = v > 0.f ? v : 0.f;
    }
  }
}

// conv2: 64-thr blocks, grid (pos-tile=11, n=128, ocq=4), 16 accs/thread
__global__ __launch_bounds__(64) void conv2_kernel(
    const float* __restrict__ in,  // f1 128x32x55x55
    const float* __restrict__ wt,  // [512][64]
    const float* __restrict__ bias, float* __restrict__ out) {
  int n = blockIdx.y;
  int ob0 = blockIdx.z * 16;                 // 0,16,32,48
  int pos = blockIdx.x * 64 + threadIdx.x;   // active < 676
  float acc[16];
#pragma unroll
  for (int o = 0; o < 16; ++o) acc[o] = 0.f;
  if (pos < 676) {
    int oh = pos / 26, ow = pos % 26;
    const float* ib = in + (size_t)n * 32 * 55 * 55 + (oh * 2) * 55 + ow * 2;
    const float* wb = wt + ob0;
#pragma unroll 2
    for (int c = 0; c < 32; ++c) {
#pragma unroll
      for (int kh = 0; kh < 4; ++kh) {
        const float* row = ib + c * 55 * 55 + kh * 55;
#pragma unroll
        for (int kw = 0; kw < 4; ++kw) {
          float px = row[kw];
          int k = (c * 4 + kh) * 4 + kw;
#pragma unroll
          for (int o = 0; o < 16; ++o)
            acc[o] = fmaf(px, wb[k * 64 + o], acc[o]);
        }
      }
    }
    float* obp = out + ((size_t)(n * 64 + ob0) * 26 + oh) * 26 + ow;
#pragma unroll
    for (int o = 0; o < 16; ++o) {
      float v = acc[o] + bias[ob0 + o];
      obp[(size_t)o * 26 * 26] = v > 0.f ? v : 0.f;
    }
  }
}

// conv3: 64-thr blocks, grid (pos-tile=9, n=128, ocq=4), 16 accs/thread
__global__ __launch_bounds__(64) void conv3_kernel(
    const float* __restrict__ in,  // f2 128x64x26x26
    const float* __restrict__ wt,  // [576][64]
    const float* __restrict__ bias, float* __restrict__ x) {
  int n = blockIdx.y;
  int ob0 = blockIdx.z * 16;                 // 0,16,32,48
  int pos = blockIdx.x * 64 + threadIdx.x;   // < 576 always
  int oh = pos / 24, ow = pos % 24;
  float acc[16];
#pragma unroll
  for (int o = 0; o < 16; ++o) acc[o] = 0.f;
  const float* wb = wt + ob0;
#pragma unroll 2
  for (int c = 0; c < 64; ++c) {
#pragma unroll
    for (int kh = 0; kh < 3; ++kh) {
      const float* row = in + ((size_t)(n * 64 + c) * 26 + oh + kh) * 26 + ow;
#pragma unroll
      for (int kw = 0; kw < 3; ++kw) {
        float px = row[kw];
        int k = (c * 3 + kh) * 3 + kw;
#pragma unroll
        for (int o = 0; o < 16; ++o)
          acc[o] = fmaf(px, wb[k * 64 + o], acc[o]);
      }
    }
  }
  float* xb = x + (size_t)n * XS + pos;
#pragma unroll
  for (int o = 0; o < 16; ++o) {
    float v = acc[o] + bias[ob0 + o];
    xb[(size_t)(ob0 + o) * 576] = v > 0.f ? v : 0.f;
  }
}

// history -> x[:, 36864:36954], zero the pad to 36960
__global__ __launch_bounds__(256) void histpack_kernel(
    const float* __restrict__ h, float* __restrict__ x) {
  int i = blockIdx.x * 256 + threadIdx.x;
  if (i < 128 * 96) {
    int n = i / 96, k = i % 96;
    x[(size_t)n * XS + 36864 + k] = (k < 90) ? h[n * 90 + k] : 0.f;
  }
}

// FC1: register-blocked split-K GEMM. Block kt covers k in [kt*128, kt*128+128)
// as 4 staged chunks of KC=32. Full 128b x 128j tile per block; thread owns
// an 8b x 8j interleaved sub-tile (b = bq+16*bb, j = jq+16*jj) -> 64 accs,
// 256 FMA per 16 ds_read_b128. LDS rows padded to 36 floats (stride 4 mod 32
// banks -> worst 2-way aliasing = free). P[kt][b][j] partials, deterministic.
#define FC1_KT 289
__global__ __launch_bounds__(256) void fc1_kernel(
    const float* __restrict__ x, const float* __restrict__ w1p,
    float* __restrict__ P) {
  int kt = blockIdx.x;        // 0..288
  int t  = threadIdx.x;
  int bq = t & 15, jq = t >> 4;
  __shared__ float xs[128 * 36];
  __shared__ float wsm[128 * 36];
  float acc[8][8];
#pragma unroll
  for (int bb = 0; bb < 8; ++bb)
#pragma unroll
    for (int jj = 0; jj < 8; ++jj) acc[bb][jj] = 0.f;

  int cs = t & 7;          // float4 column for staging (0..7)
  int rs = t >> 3;         // row base for staging (0..31), 4 passes
#pragma unroll 1
  for (int s = 0; s < 4; ++s) {
    int k0 = kt * 128 + s * 32;
    __syncthreads();
#pragma unroll
    for (int p = 0; p < 4; ++p) {
      int r = rs + p * 32;
      int gk = k0 + cs * 4;
      float4 xv, wv;
      if (gk < 36954) {
        xv = *(const float4*)&x[(size_t)r * XS + gk];
        wv = *(const float4*)&w1p[(size_t)r * XS + gk];
      } else {
        xv = make_float4(0.f, 0.f, 0.f, 0.f);
        wv = make_float4(0.f, 0.f, 0.f, 0.f);
      }
      *(float4*)&xs[r * 36 + cs * 4] = xv;
      *(float4*)&wsm[r * 36 + cs * 4] = wv;
    }
    __syncthreads();
#pragma unroll 1
    for (int kk = 0; kk < 32; kk += 4) {
      float4 xv[8], wv[8];
#pragma unroll
      for (int i = 0; i < 8; ++i)
        xv[i] = *(const float4*)&xs[(bq + 16 * i) * 36 + kk];
#pragma unroll
      for (int i = 0; i < 8; ++i)
        wv[i] = *(const float4*)&wsm[(jq + 16 * i) * 36 + kk];
#pragma unroll
      for (int bb = 0; bb < 8; ++bb)
#pragma unroll
        for (int jj = 0; jj < 8; ++jj) {
          acc[bb][jj] = fmaf(xv[bb].x, wv[jj].x, acc[bb][jj]);
          acc[bb][jj] = fmaf(xv[bb].y, wv[jj].y, acc[bb][jj]);
          acc[bb][jj] = fmaf(xv[bb].z, wv[jj].z, acc[bb][jj]);
          acc[bb][jj] = fmaf(xv[bb].w, wv[jj].w, acc[bb][jj]);
        }
    }
  }
  float* Pb = P + (size_t)kt * 16384;
#pragma unroll
  for (int bb = 0; bb < 8; ++bb)
#pragma unroll
    for (int jj = 0; jj < 8; ++jj)
      Pb[(bq + 16 * bb) * 128 + jq + 16 * jj] = acc[bb][jj];
}

// Recurrence: one block per batch row; reduces P partials then runs T=10.
__global__ __launch_bounds__(256) void recur_kernel(
    const float* __restrict__ P,    // [289][128][128]
    const float* __restrict__ b1,
    const float* __restrict__ w2t,  // [128][256]
    const float* __restrict__ b2,
    const float* __restrict__ w3,   // [9][256]
    const float* __restrict__ b3,
    float* __restrict__ out) {      // [128][9]
  int b = blockIdx.x;
  int t = threadIdx.x;
  __shared__ float spk1s[128];
  __shared__ float spk2s[256];
  float h1 = 0.f, mem1 = 0.f, syn1 = 0.f;
  if (t < 128) {
    h1 = b1[t];
    for (int kt = 0; kt < FC1_KT; ++kt)
      h1 += P[((size_t)kt * 128 + b) * 128 + t];
  }
  float mem2 = 0.f, syn2 = 0.f;
  float b2v = b2[t];
  float mem3 = 0.f, syn3 = 0.f, pot = 0.f;
  float b3v = (t < 9) ? b3[t] : 0.f;

  for (int step = 0; step < 10; ++step) {
    if (t < 128) {
      syn1 = ALPHA * syn1 + h1;
      mem1 = BETA * mem1 + syn1;
      float s = (mem1 > 1.0f) ? 1.0f : 0.0f;
      mem1 -= s;
      spk1s[t] = s;
    }
    __syncthreads();
    float h2 = b2v;
#pragma unroll 8
    for (int k = 0; k < 128; ++k)
      h2 = fmaf(spk1s[k], w2t[k * 256 + t], h2);
    syn2 = ALPHA * syn2 + h2;
    mem2 = BETA * mem2 + syn2;
    float s2 = (mem2 > 1.0f) ? 1.0f : 0.0f;
    mem2 -= s2;
    spk2s[t] = s2;
    __syncthreads();
    if (t < 9) {
      float a0 = 0.f, a1 = 0.f, a2 = 0.f, a3 = 0.f;
      const float* wr = w3 + t * 256;
      for (int k = 0; k < 256; k += 4) {
        a0 = fmaf(spk2s[k],     wr[k],     a0);
        a1 = fmaf(spk2s[k + 1], wr[k + 1], a1);
        a2 = fmaf(spk2s[k + 2], wr[k + 2], a2);
        a3 = fmaf(spk2s[k + 3], wr[k + 3], a3);
      }
      float h3 = b3v + (a0 + a1) + (a2 + a3);
      syn3 = ALPHA * syn3 + h3;
      mem3 = BETA * mem3 + syn3;
      pot += mem3;
    }
    __syncthreads();
  }
  if (t < 9) out[b * 9 + t] = pot * 0.1f;
}

extern "C" void kernel_launch(void* const* d_in, const int* in_sizes, int n_in,
                              void* d_out, int out_size, void* d_ws, size_t ws_size,
                              hipStream_t stream) {
  const float* state   = (const float*)d_in[0];
  const float* history = (const float*)d_in[1];
  const float* cw1 = (const float*)d_in[2];
  const float* cb1 = (const float*)d_in[3];
  const float* cw2 = (const float*)d_in[4];
  const float* cb2 = (const float*)d_in[5];
  const float* cw3 = (const float*)d_in[6];
  const float* cb3 = (const float*)d_in[7];
  const float* w1  = (const float*)d_in[8];
  const float* b1  = (const float*)d_in[9];
  const float* w2  = (const float*)d_in[10];
  const float* b2  = (const float*)d_in[11];
  const float* w3  = (const float*)d_in[12];
  const float* b3  = (const float*)d_in[13];
  float* out = (float*)d_out;
  char* ws = (char*)d_ws;

  // workspace layout (bytes):
  //  [0, 49561600)   f1 (live conv1->conv2). After conv2:
  //                    xb  = [0, 18923520)          (128 x 36960)
  //                    w1p = [18923520, 37847040)   (128 x 36960)
  //  [49561600, 71712768)  f2 (live conv2->conv3). After conv3:
  //                    P   = [49561600, +18939904)  (289 x 128 x 128)
  //  [71712768, ...)       small transposed weights
  float* f1  = (float*)(ws + 0);
  float* xb  = (float*)(ws + 0);
  float* w1p = (float*)(ws + 18923520);
  float* f2  = (float*)(ws + 49561600);
  float* P   = (float*)(ws + 49561600);
  float* wt1 = (float*)(ws + 71712768);   // 24,576
  float* wt2 = (float*)(ws + 71737344);   // 131,072
  float* wt3 = (float*)(ws + 71868416);   // 147,456
  float* w2t = (float*)(ws + 72015872);   // 131,072  (end 72,146,944)

  transpose_weights_kernel<<<144, 256, 0, stream>>>(cw1, cw2, cw3, w2,
                                                    wt1, wt2, wt3, w2t);
  conv1_kernel<<<dim3(55, 128), 64, 0, stream>>>(state, wt1, cb1, f1);
  conv2_kernel<<<dim3(11, 128, 4), 64, 0, stream>>>(f1, wt2, cb2, f2);
  pad_w1_kernel<<<9240, 256, 0, stream>>>(w1, w1p);
  conv3_kernel<<<dim3(9, 128, 4), 64, 0, stream>>>(f2, wt3, cb3, xb);
  histpack_kernel<<<48, 256, 0, stream>>>(history, xb);
  fc1_kernel<<<FC1_KT, 256, 0, stream>>>(xb, w1p, P);
  recur_kernel<<<128, 256, 0, stream>>>(P, b1, w2t, b2, w3, b3, out);
}